// Round 9
// baseline (116.754 us; speedup 1.0000x reference)
//
#include <hip/hip_runtime.h>
#include <hip/hip_bf16.h>

// Problem constants (Atten_tit): B=16, T=256, K=256, H=512, A=49
#define B_ 16
#define T_ 256
#define K_ 256
#define H_ 512
#define A_ 49
#define APAD 64
#define GRID 256
#define WPAD 264   // ushort stride for 256-col W half-slice (+8 pad)

typedef __attribute__((ext_vector_type(8))) short short8;   // bf16x8
typedef __attribute__((ext_vector_type(4))) float f32x4;

__device__ __forceinline__ ushort f2bf(float f) {
    uint u = __builtin_bit_cast(uint, f);
    u += 0x7FFF + ((u >> 16) & 1);   // RNE
    return (ushort)(u >> 16);
}

// split f32 -> bf16 hi + bf16 lo (residual); hi+lo ~ 17 mantissa bits.
__device__ __forceinline__ void cvt_hilo(float4 v0, float4 v1, short8& hi, short8& lo) {
    float v[8] = {v0.x, v0.y, v0.z, v0.w, v1.x, v1.y, v1.z, v1.w};
    #pragma unroll
    for (int i = 0; i < 8; ++i) {
        ushort h = f2bf(v[i]);
        float hf = __builtin_bit_cast(float, (uint)h << 16);
        hi[i] = (short)h;
        lo[i] = (short)f2bf(v[i] - hf);
    }
}

// 1/(exp(2x)+1); tanh(x) = 1 - 2*sig2(x). exp saturation handles extremes.
__device__ __forceinline__ float sig2(float x) {
    float e = __expf(2.f * x);
    return __builtin_amdgcn_rcpf(e + 1.f);
}

struct SMproj { ushort whi[16][WPAD]; ushort wlo[16][WPAD]; };   // 16896 B
struct SMtr   { float t[4][32][33]; };                            // 16896 B
struct SMz    { float cg[16][APAD]; float wh[APAD];
                float redM[16][4]; float redS[16][4];
                ushort a[16][K_ + 8]; };                          // 13312 B
union SMu { SMproj p; SMtr tr; SMz z; };

// ---------------------------------------------------------------------------
// Fused kernel, 256 blocks x 1024 threads, all co-resident.
// XCD-homing: block bid runs on XCD bid%8 (round-robin dispatch heuristic).
// P0 proj  (bid<128):  bid = (tg16&7) | (g<<3) | ((tg16>>3)<<5); writes for
//   batch b = tg16 (des->cvT) or tg16-16 (title->cg) land on XCD b%8.
// P0 trans (bid>=128): x=bid-128 = (b&7)+8*(b>>3)+16*ck; block handles
//   k-stripe ck (32 k) x all 512 h of batch b -> desT[b] stays on XCD b%8.
// P1 (all): b = bid&15 -> XCD b%8 == writer XCD. cvT/cg/desT reads are L2-local.
__global__ __launch_bounds__(1024) void kFused(const float* __restrict__ des,
                                               const float* __restrict__ title,
                                               const float* __restrict__ Wv,
                                               const float* __restrict__ Wg,
                                               const float* __restrict__ Wh,
                                               float* __restrict__ alpha,
                                               float* __restrict__ chat,
                                               float* __restrict__ cvT,
                                               float* __restrict__ cg,
                                               ushort* __restrict__ desT,
                                               uint* __restrict__ counter)
{
    __shared__ SMu sm;
    int tid = threadIdx.x;
    int bid = blockIdx.x;

    // ================= P0 =================
    if (bid < 128) {
        // ---- projection (split-bf16 MFMA) ----
        int g    = (bid >> 3) & 3;
        int tg16 = (bid & 7) | ((bid >> 5) << 3);   // 0..31
        bool isDes = tg16 < 16;
        const float* W = isDes ? Wv : Wg;

        int wv = tid >> 6, lane = tid & 63;
        int lr = lane & 15, lc = lane >> 4;
        int tile = tg16 * 16 + wv;                  // 0..511
        const float* X = isDes ? (des + (size_t)tile * 16 * H_)
                               : (title + (size_t)(tile - 256) * 16 * H_);
        const float* xp0 = X + (size_t)lr * H_ + lc * 8;

        f32x4 acc = {};
        #pragma unroll
        for (int half = 0; half < 2; ++half) {
            {   // stage W rows [g*16,+16), cols [half*256,+256) as hi/lo
                int row = tid >> 6;            // 0..15
                int c0  = (tid & 63) * 4;      // 0..252
                int a = g * 16 + row;
                float4 v = make_float4(0.f, 0.f, 0.f, 0.f);
                if (a < A_) v = *(const float4*)(W + (size_t)a * H_ + half * 256 + c0);
                float vv[4] = {v.x, v.y, v.z, v.w};
                ushort4 h4, l4;
                ushort* hp = (ushort*)&h4; ushort* lp = (ushort*)&l4;
                #pragma unroll
                for (int i = 0; i < 4; ++i) {
                    ushort h = f2bf(vv[i]);
                    float hf = __builtin_bit_cast(float, (uint)h << 16);
                    hp[i] = h;
                    lp[i] = f2bf(vv[i] - hf);
                }
                *(ushort4*)&sm.p.whi[row][c0] = h4;
                *(ushort4*)&sm.p.wlo[row][c0] = l4;
            }
            __syncthreads();
            #pragma unroll
            for (int kk = 0; kk < 256; kk += 32) {
                int k0 = half * 256 + kk;
                float4 xv0 = *(const float4*)(xp0 + k0);
                float4 xv1 = *(const float4*)(xp0 + k0 + 4);
                short8 xhi, xlo;
                cvt_hilo(xv0, xv1, xhi, xlo);
                short8 whi = *(const short8*)&sm.p.whi[lr][kk + lc * 8];
                short8 wlo = *(const short8*)&sm.p.wlo[lr][kk + lc * 8];
                if (isDes) {   // C[a][k-row]
                    acc = __builtin_amdgcn_mfma_f32_16x16x32_bf16(whi, xhi, acc, 0, 0, 0);
                    acc = __builtin_amdgcn_mfma_f32_16x16x32_bf16(whi, xlo, acc, 0, 0, 0);
                    acc = __builtin_amdgcn_mfma_f32_16x16x32_bf16(wlo, xhi, acc, 0, 0, 0);
                } else {       // C[t][a]
                    acc = __builtin_amdgcn_mfma_f32_16x16x32_bf16(xhi, whi, acc, 0, 0, 0);
                    acc = __builtin_amdgcn_mfma_f32_16x16x32_bf16(xlo, whi, acc, 0, 0, 0);
                    acc = __builtin_amdgcn_mfma_f32_16x16x32_bf16(xhi, wlo, acc, 0, 0, 0);
                }
            }
            __syncthreads();
        }

        if (isDes) {
            int krows = tile * 16;
            int b = krows >> 8, kb = krows & 255;
            #pragma unroll
            for (int r = 0; r < 4; ++r) {
                int a = g * 16 + lc * 4 + r;
                cvT[((size_t)b * APAD + a) * K_ + kb + lr] = acc[r];
            }
        } else {
            int trows = (tile - 256) * 16;
            #pragma unroll
            for (int r = 0; r < 4; ++r) {
                int row = trows + lc * 4 + r;
                cg[(size_t)row * APAD + g * 16 + lr] = acc[r];
            }
        }
    } else {
        // ---- transpose: batch b, k-stripe ck; 16 h-subtiles (4 conc x 4 it) ----
        int x  = bid - 128;
        int b  = (x & 7) | (((x >> 3) & 1) << 3);
        int ck = x >> 4;                  // 0..7
        int k0 = ck * 32;
        int grp = tid >> 8, st2 = tid & 255;
        int kk = st2 >> 3, c4 = (st2 & 7) * 4;
        #pragma unroll
        for (int it = 0; it < 4; ++it) {
            int h0 = (it * 4 + grp) * 32;
            float4 v = *(const float4*)(des + ((size_t)(b * K_ + k0 + kk) * H_) + h0 + c4);
            sm.tr.t[grp][kk][c4 + 0] = v.x;
            sm.tr.t[grp][kk][c4 + 1] = v.y;
            sm.tr.t[grp][kk][c4 + 2] = v.z;
            sm.tr.t[grp][kk][c4 + 3] = v.w;
            __syncthreads();
            ushort4 o;
            o.x = f2bf(sm.tr.t[grp][c4 + 0][kk]);
            o.y = f2bf(sm.tr.t[grp][c4 + 1][kk]);
            o.z = f2bf(sm.tr.t[grp][c4 + 2][kk]);
            o.w = f2bf(sm.tr.t[grp][c4 + 3][kk]);
            *(ushort4*)(desT + ((size_t)(b * H_ + h0 + kk) * K_) + k0 + c4) = o;
            __syncthreads();
        }
    }

    // ================= grid barrier =================
    __syncthreads();
    if (tid == 0) {
        __hip_atomic_fetch_add(counter, 1u, __ATOMIC_ACQ_REL, __HIP_MEMORY_SCOPE_AGENT);
        while (__hip_atomic_load(counter, __ATOMIC_ACQUIRE, __HIP_MEMORY_SCOPE_AGENT) < GRID)
            __builtin_amdgcn_s_sleep(8);
    }
    __syncthreads();

    // ================= P1: z + softmax + PV =================
    int b  = bid & 15;                    // XCD-local b
    int t0 = (bid >> 4) << 4;
    int k  = tid & 255;
    int tg = tid >> 8;                    // 0..3
    int tb = tg * 4;

    if (tid < 256) {
        int row = tid >> 4, c = (tid & 15) * 4;
        *(float4*)(&sm.z.cg[row][c]) =
            *(const float4*)(cg + (size_t)(b * T_ + t0 + row) * APAD + c);
    } else if (tid < 256 + APAD) {
        int a = tid - 256;
        sm.z.wh[a] = (a < A_) ? Wh[a] : 0.f;
    }
    __syncthreads();

    // ---- z phase: 8-deep ping-pong prefetch of xa (forces MLP) ----
    const float* cvp = cvT + (size_t)b * APAD * K_ + k;
    float zacc[4] = {0.f, 0.f, 0.f, 0.f};

    float xaA[8], xaB[8];
    #pragma unroll
    for (int i = 0; i < 8; ++i) xaA[i] = cvp[(size_t)i * K_];

#define CONSUME(xa, a0) { \
    float4 w0 = *(const float4*)&sm.z.wh[(a0)]; \
    float4 w1 = *(const float4*)&sm.z.wh[(a0) + 4]; \
    _Pragma("unroll") \
    for (int j = 0; j < 4; ++j) { \
        float4 c0 = *(const float4*)&sm.z.cg[tb + j][(a0)]; \
        float4 c1 = *(const float4*)&sm.z.cg[tb + j][(a0) + 4]; \
        zacc[j] += w0.x * sig2(xa[0] + c0.x) + w0.y * sig2(xa[1] + c0.y) \
                 + w0.z * sig2(xa[2] + c0.z) + w0.w * sig2(xa[3] + c0.w) \
                 + w1.x * sig2(xa[4] + c1.x) + w1.y * sig2(xa[5] + c1.y) \
                 + w1.z * sig2(xa[6] + c1.z) + w1.w * sig2(xa[7] + c1.w); \
    } }

    #pragma unroll
    for (int i = 0; i < 8; ++i) xaB[i] = cvp[(size_t)(8 + i) * K_];
    CONSUME(xaA, 0)
    #pragma unroll
    for (int i = 0; i < 8; ++i) xaA[i] = cvp[(size_t)(16 + i) * K_];
    CONSUME(xaB, 8)
    #pragma unroll
    for (int i = 0; i < 8; ++i) xaB[i] = cvp[(size_t)(24 + i) * K_];
    CONSUME(xaA, 16)
    #pragma unroll
    for (int i = 0; i < 8; ++i) xaA[i] = cvp[(size_t)(32 + i) * K_];
    CONSUME(xaB, 24)
    #pragma unroll
    for (int i = 0; i < 8; ++i) xaB[i] = cvp[(size_t)(40 + i) * K_];
    CONSUME(xaA, 32)
    float xaT = cvp[(size_t)48 * K_];
    CONSUME(xaB, 40)
    {   // tail a = 48
        float wh = sm.z.wh[48];
        #pragma unroll
        for (int j = 0; j < 4; ++j)
            zacc[j] += wh * sig2(xaT + sm.z.cg[tb + j][48]);
    }
#undef CONSUME

    float sw = 0.f;
    #pragma unroll
    for (int q = 0; q < 16; ++q) {
        float4 w4 = *(const float4*)&sm.z.wh[q * 4];
        sw += w4.x + w4.y + w4.z + w4.w;
    }
    float z[4];
    #pragma unroll
    for (int j = 0; j < 4; ++j) z[j] = sw - 2.f * zacc[j];

    // ---- softmax over k ----
    int wv = tid >> 6, lane = tid & 63, w3 = wv & 3;
    #pragma unroll
    for (int j = 0; j < 4; ++j) {
        float m = z[j];
        #pragma unroll
        for (int off = 32; off > 0; off >>= 1) m = fmaxf(m, __shfl_xor(m, off));
        if (lane == 0) sm.z.redM[tb + j][w3] = m;
    }
    __syncthreads();
    #pragma unroll
    for (int j = 0; j < 4; ++j) {
        int t = tb + j;
        float m = fmaxf(fmaxf(sm.z.redM[t][0], sm.z.redM[t][1]),
                        fmaxf(sm.z.redM[t][2], sm.z.redM[t][3]));
        z[j] = __expf(z[j] - m);
    }
    #pragma unroll
    for (int j = 0; j < 4; ++j) {
        float s = z[j];
        #pragma unroll
        for (int off = 32; off > 0; off >>= 1) s += __shfl_xor(s, off);
        if (lane == 0) sm.z.redS[tb + j][w3] = s;
    }
    __syncthreads();
    #pragma unroll
    for (int j = 0; j < 4; ++j) {
        int t = tb + j;
        float s = sm.z.redS[t][0] + sm.z.redS[t][1] + sm.z.redS[t][2] + sm.z.redS[t][3];
        float rs = __builtin_amdgcn_rcpf(s);
        rs = rs * (2.f - s * rs);              // Newton step
        float al = z[j] * rs;
        alpha[(size_t)(b * T_ + t0 + t) * K_ + k] = al;
        sm.z.a[t][k] = f2bf(al);
    }
    __syncthreads();

    // ---- PV: wave wv -> h-panel [wv*32, +32), 4-deep global loads ----
    int lr = lane & 15, lc = lane >> 4;
    int h0 = wv * 32;
    const ushort* Bp = desT + ((size_t)(b * H_ + h0 + lr)) * K_ + lc * 8;

    f32x4 acc0 = {}, acc1 = {};
    #pragma unroll
    for (int kb = 0; kb < K_; kb += 64) {
        short8 b00 = *(const short8*)(Bp + kb);
        short8 b01 = *(const short8*)(Bp + (size_t)16 * K_ + kb);
        short8 b10 = *(const short8*)(Bp + kb + 32);
        short8 b11 = *(const short8*)(Bp + (size_t)16 * K_ + kb + 32);
        short8 a80 = *(const short8*)(&sm.z.a[lr][kb + lc * 8]);
        short8 a81 = *(const short8*)(&sm.z.a[lr][kb + 32 + lc * 8]);
        acc0 = __builtin_amdgcn_mfma_f32_16x16x32_bf16(a80, b00, acc0, 0, 0, 0);
        acc1 = __builtin_amdgcn_mfma_f32_16x16x32_bf16(a80, b01, acc1, 0, 0, 0);
        acc0 = __builtin_amdgcn_mfma_f32_16x16x32_bf16(a81, b10, acc0, 0, 0, 0);
        acc1 = __builtin_amdgcn_mfma_f32_16x16x32_bf16(a81, b11, acc1, 0, 0, 0);
    }

    #pragma unroll
    for (int r = 0; r < 4; ++r) {
        int row = t0 + lc * 4 + r;
        chat[((size_t)(b * T_ + row)) * H_ + h0 + lr]      = acc0[r];
        chat[((size_t)(b * T_ + row)) * H_ + h0 + 16 + lr] = acc1[r];
    }
}

// ---------------------------------------------------------------------------
extern "C" void kernel_launch(void* const* d_in, const int* in_sizes, int n_in,
                              void* d_out, int out_size, void* d_ws, size_t ws_size,
                              hipStream_t stream) {
    const float* des   = (const float*)d_in[0];
    const float* title = (const float*)d_in[1];
    const float* Wv    = (const float*)d_in[2];
    const float* Wg    = (const float*)d_in[3];
    const float* Wh    = (const float*)d_in[4];

    float* chat  = (float*)d_out;                            // (B,T,H)
    float* alpha = (float*)d_out + (size_t)B_ * T_ * H_;     // (B,T,K)

    char* ws = (char*)d_ws;
    float*  cvT  = (float*)ws;                               // (B,64,K) f32: 1 MB
    float*  cg   = cvT + (size_t)B_ * APAD * K_;             // (B*T,64) f32: 1 MB
    ushort* desT = (ushort*)(cg + (size_t)B_ * T_ * APAD);   // (B,H,K) bf16: 4 MB
    uint* counter = (uint*)(desT + (size_t)B_ * H_ * K_);    // barrier counter

    hipMemsetAsync(counter, 0, 128, stream);                 // graph-safe reset
    hipLaunchKernelGGL(kFused, dim3(GRID), dim3(1024), 0, stream,
                       des, title, Wv, Wg, Wh, alpha, chat, cvT, cg, desT, counter);
}

// Round 10
// 95.658 us; speedup vs baseline: 1.2205x; 1.2205x over previous
//
#include <hip/hip_runtime.h>
#include <hip/hip_bf16.h>

// Problem constants (Atten_tit): B=16, T=256, K=256, H=512, A=49
#define B_ 16
#define T_ 256
#define K_ 256
#define H_ 512
#define A_ 49
#define APAD 64

typedef __attribute__((ext_vector_type(8))) short short8;   // bf16x8
typedef __attribute__((ext_vector_type(4))) float f32x4;

__device__ __forceinline__ ushort f2bf(float f) {
    uint u = __builtin_bit_cast(uint, f);
    u += 0x7FFF + ((u >> 16) & 1);   // RNE
    return (ushort)(u >> 16);
}

// split f32 -> bf16 hi + bf16 lo (residual); hi+lo ~ 17 mantissa bits.
__device__ __forceinline__ void cvt_hilo(float4 v0, float4 v1, short8& hi, short8& lo) {
    float v[8] = {v0.x, v0.y, v0.z, v0.w, v1.x, v1.y, v1.z, v1.w};
    #pragma unroll
    for (int i = 0; i < 8; ++i) {
        ushort h = f2bf(v[i]);
        float hf = __builtin_bit_cast(float, (uint)h << 16);
        hi[i] = (short)h;
        lo[i] = (short)f2bf(v[i] - hf);
    }
}

// 1/(exp(2x)+1); tanh(x) = 1 - 2*sig2(x). exp saturation handles extremes.
__device__ __forceinline__ float sig2(float x) {
    float e = __expf(2.f * x);
    return __builtin_amdgcn_rcpf(e + 1.f);
}

// ---------------------------------------------------------------------------
// kW: Wv,Wg (49x512 f32) -> Whl[m][hl][64][512] bf16, rows >=49 zeroed.
__global__ __launch_bounds__(256) void kW(const float* __restrict__ Wv,
                                          const float* __restrict__ Wg,
                                          ushort* __restrict__ Whl)
{
    int blk = blockIdx.x;              // 0..127: m = blk>>6, row = blk&63
    int m = blk >> 6, row = blk & 63;
    const float* W = m ? Wg : Wv;
    int tid = threadIdx.x;
    ushort* hi = Whl + ((size_t)(m * 2 + 0) * 64 + row) * H_;
    ushort* lo = Whl + ((size_t)(m * 2 + 1) * 64 + row) * H_;
    #pragma unroll
    for (int c = tid; c < H_; c += 256) {
        float v = (row < A_) ? W[(size_t)row * H_ + c] : 0.f;
        ushort h = f2bf(v);
        float hf = __builtin_bit_cast(float, (uint)h << 16);
        hi[c] = h;
        lo[c] = f2bf(v - hf);
    }
}

// ---------------------------------------------------------------------------
// kAP: blocks [0,512): projection via split-bf16 MFMA, 1 tile/wave, W from
//      global Whl (L2-resident), 2-deep X prefetch. X read exactly once.
//        tiles 0..255   (des):   C = W x des-rows -> cvT (B,64,K)
//        tiles 256..511 (title): C = title-rows x W -> cg (B*T,64)
//      blocks [512,2560): transpose des (B,K,H) f32 -> desT (B,H,K) bf16.
__global__ __launch_bounds__(256, 2) void kAP(const float* __restrict__ des,
                                              const float* __restrict__ title,
                                              const ushort* __restrict__ Whl,
                                              float* __restrict__ cvT,
                                              float* __restrict__ cg,
                                              ushort* __restrict__ desT)
{
    __shared__ float Tls[32][33];
    int tid = threadIdx.x;

    if (blockIdx.x >= 512) {
        // ---- transpose branch (round-7 proven) ----
        int tb = blockIdx.x - 512;            // b(16) x kt(8) x ht(16)
        int b = tb >> 7, rem = tb & 127;
        int k0 = (rem >> 4) * 32, h0 = (rem & 15) * 32;
        int kk = tid >> 3, c4 = (tid & 7) * 4;
        float4 v = *(const float4*)(des + ((size_t)(b * K_ + k0 + kk) * H_) + h0 + c4);
        Tls[kk][c4 + 0] = v.x; Tls[kk][c4 + 1] = v.y;
        Tls[kk][c4 + 2] = v.z; Tls[kk][c4 + 3] = v.w;
        __syncthreads();
        int hh = tid >> 3;
        ushort4 o;
        o.x = f2bf(Tls[c4 + 0][hh]);
        o.y = f2bf(Tls[c4 + 1][hh]);
        o.z = f2bf(Tls[c4 + 2][hh]);
        o.w = f2bf(Tls[c4 + 3][hh]);
        *(ushort4*)(desT + ((size_t)(b * H_ + h0 + hh) * K_) + k0 + c4) = o;
        return;
    }

    // ---- projection branch ----
    int wv = tid >> 6, lane = tid & 63;
    int tile = blockIdx.x;                    // 0..511
    bool isDes = tile < 256;
    int lr = lane & 15, lc = lane >> 4;
    int g = wv;                               // a-group 0..3

    const float* X = isDes ? (des + (size_t)tile * 16 * H_)
                           : (title + (size_t)(tile - 256) * 16 * H_);
    int m = isDes ? 0 : 1;
    const ushort* whiP = Whl + ((size_t)(m * 2 + 0) * 64 + g * 16 + lr) * H_ + lc * 8;
    const ushort* wloP = Whl + ((size_t)(m * 2 + 1) * 64 + g * 16 + lr) * H_ + lc * 8;
    const float*  xp0  = X + (size_t)lr * H_ + lc * 8;

    f32x4 acc = {};
    float4 xv0 = *(const float4*)(xp0);
    float4 xv1 = *(const float4*)(xp0 + 4);

    #pragma unroll
    for (int i = 0; i < 16; ++i) {
        int k0 = i * 32;
        float4 nx0, nx1;
        if (i < 15) {                     // 2-deep prefetch of next X fragment
            nx0 = *(const float4*)(xp0 + k0 + 32);
            nx1 = *(const float4*)(xp0 + k0 + 36);
        }
        short8 whi = *(const short8*)(whiP + k0);
        short8 wlo = *(const short8*)(wloP + k0);
        short8 xhi, xlo;
        cvt_hilo(xv0, xv1, xhi, xlo);
        if (isDes) {     // A = W (rows=a), B = X (cols = k-row of des)
            acc = __builtin_amdgcn_mfma_f32_16x16x32_bf16(whi, xhi, acc, 0, 0, 0);
            acc = __builtin_amdgcn_mfma_f32_16x16x32_bf16(whi, xlo, acc, 0, 0, 0);
            acc = __builtin_amdgcn_mfma_f32_16x16x32_bf16(wlo, xhi, acc, 0, 0, 0);
        } else {         // A = X (rows=t), B = W (cols=a)
            acc = __builtin_amdgcn_mfma_f32_16x16x32_bf16(xhi, whi, acc, 0, 0, 0);
            acc = __builtin_amdgcn_mfma_f32_16x16x32_bf16(xlo, whi, acc, 0, 0, 0);
            acc = __builtin_amdgcn_mfma_f32_16x16x32_bf16(xhi, wlo, acc, 0, 0, 0);
        }
        if (i < 15) { xv0 = nx0; xv1 = nx1; }
    }

    if (isDes) {
        int krows = tile * 16;
        int b = krows >> 8, kb = krows & 255;
        #pragma unroll
        for (int r = 0; r < 4; ++r) {
            int a = g * 16 + lc * 4 + r;           // C row = a
            cvT[((size_t)b * APAD + a) * K_ + kb + lr] = acc[r];
        }
    } else {
        int trows = (tile - 256) * 16;             // global title row (b*T+t)
        #pragma unroll
        for (int r = 0; r < 4; ++r) {
            int row = trows + lc * 4 + r;          // C row = t
            cg[(size_t)row * APAD + g * 16 + lr] = acc[r];
        }
    }
}

// ---------------------------------------------------------------------------
// kZ: fused z + softmax + PV. One block per (b, 16-row t-tile). 1024 threads.
// b = bid&15 (XCD round-robin keeps desT[b]/cvT[b] L2-local per XCD).
// cv[b] (49x256 f32, 49 KB) staged in LDS once -> z inner loop is LDS+VALU only.
// Thread (k = tid&255, tg = tid>>8) owns t = tg*4 + {0..3}.
__global__ __launch_bounds__(1024) void kZ(const float* __restrict__ cvT,
                                           const float* __restrict__ cg,
                                           const float* __restrict__ Wh,
                                           const ushort* __restrict__ desT,
                                           float* __restrict__ alpha,
                                           float* __restrict__ chat)
{
    __shared__ float  sCv[A_][K_];         // 50176 B
    __shared__ float  sCg[16][APAD];       // 4096 B
    __shared__ float  sWh[APAD];           // 256 B
    __shared__ float  sRedM[16][4];        // 256 B
    __shared__ float  sRedS[16][4];        // 256 B
    __shared__ ushort sA[16][K_ + 8];      // 8448 B   (total ~62 KB)

    int bid = blockIdx.x;                 // 256 blocks
    int b  = bid & 15;
    int t0 = (bid >> 4) << 4;
    int tid = threadIdx.x;
    int k  = tid & 255;
    int tg = tid >> 8;                    // 0..3
    int tb = tg * 4;

    {   // stage cv[b] rows 0..48 (12544 f32 = 3136 float4, contiguous)
        const float4* src = (const float4*)(cvT + (size_t)b * APAD * K_);
        float4* dst = (float4*)&sCv[0][0];
        #pragma unroll
        for (int it = 0; it < 4; ++it) {
            int idx = it * 1024 + tid;
            if (idx < (A_ * K_) / 4) dst[idx] = src[idx];
        }
    }
    if (tid < 256) {
        int row = tid >> 4, c = (tid & 15) * 4;
        *(float4*)(&sCg[row][c]) =
            *(const float4*)(cg + (size_t)(b * T_ + t0 + row) * APAD + c);
    } else if (tid < 256 + APAD) {
        int a = tid - 256;
        sWh[a] = (a < A_) ? Wh[a] : 0.f;
    }
    __syncthreads();

    // ---- z phase: pure LDS, a blocked by 8 ----
    float zacc[4] = {0.f, 0.f, 0.f, 0.f};
    #pragma unroll
    for (int c = 0; c < 6; ++c) {         // a = 0..47
        int a0 = c * 8;
        float xa[8];
        #pragma unroll
        for (int i = 0; i < 8; ++i) xa[i] = sCv[a0 + i][k];
        float4 w0 = *(const float4*)&sWh[a0];
        float4 w1 = *(const float4*)&sWh[a0 + 4];
        #pragma unroll
        for (int j = 0; j < 4; ++j) {
            float4 c0 = *(const float4*)&sCg[tb + j][a0];
            float4 c1 = *(const float4*)&sCg[tb + j][a0 + 4];
            zacc[j] += w0.x * sig2(xa[0] + c0.x) + w0.y * sig2(xa[1] + c0.y)
                     + w0.z * sig2(xa[2] + c0.z) + w0.w * sig2(xa[3] + c0.w)
                     + w1.x * sig2(xa[4] + c1.x) + w1.y * sig2(xa[5] + c1.y)
                     + w1.z * sig2(xa[6] + c1.z) + w1.w * sig2(xa[7] + c1.w);
        }
    }
    {   // tail a = 48
        float xa = sCv[48][k];
        float wh = sWh[48];
        #pragma unroll
        for (int j = 0; j < 4; ++j)
            zacc[j] += wh * sig2(xa + sCg[tb + j][48]);
    }
    float sw = 0.f;
    #pragma unroll
    for (int q = 0; q < 16; ++q) {
        float4 w4 = *(const float4*)&sWh[q * 4];
        sw += w4.x + w4.y + w4.z + w4.w;
    }
    float z[4];
    #pragma unroll
    for (int j = 0; j < 4; ++j) z[j] = sw - 2.f * zacc[j];

    // ---- softmax over k ----
    int wv = tid >> 6, lane = tid & 63, w3 = wv & 3;
    #pragma unroll
    for (int j = 0; j < 4; ++j) {
        float m = z[j];
        #pragma unroll
        for (int off = 32; off > 0; off >>= 1) m = fmaxf(m, __shfl_xor(m, off));
        if (lane == 0) sRedM[tb + j][w3] = m;
    }
    __syncthreads();
    #pragma unroll
    for (int j = 0; j < 4; ++j) {
        int t = tb + j;
        float m = fmaxf(fmaxf(sRedM[t][0], sRedM[t][1]),
                        fmaxf(sRedM[t][2], sRedM[t][3]));
        z[j] = __expf(z[j] - m);
    }
    #pragma unroll
    for (int j = 0; j < 4; ++j) {
        float s = z[j];
        #pragma unroll
        for (int off = 32; off > 0; off >>= 1) s += __shfl_xor(s, off);
        if (lane == 0) sRedS[tb + j][w3] = s;
    }
    __syncthreads();
    #pragma unroll
    for (int j = 0; j < 4; ++j) {
        int t = tb + j;
        float s = sRedS[t][0] + sRedS[t][1] + sRedS[t][2] + sRedS[t][3];
        float rs = __builtin_amdgcn_rcpf(s);
        rs = rs * (2.f - s * rs);              // Newton step
        float al = z[j] * rs;
        alpha[(size_t)(b * T_ + t0 + t) * K_ + k] = al;
        sA[t][k] = f2bf(al);
    }
    __syncthreads();

    // ---- PV: wave wv -> h-panel [wv*32, +32), 4-deep global loads ----
    int lr = lane & 15, lc = lane >> 4;
    int h0 = wv * 32;
    const ushort* Bp = desT + ((size_t)(b * H_ + h0 + lr)) * K_ + lc * 8;

    f32x4 acc0 = {}, acc1 = {};
    #pragma unroll
    for (int kb = 0; kb < K_; kb += 64) {
        short8 b00 = *(const short8*)(Bp + kb);
        short8 b01 = *(const short8*)(Bp + (size_t)16 * K_ + kb);
        short8 b10 = *(const short8*)(Bp + kb + 32);
        short8 b11 = *(const short8*)(Bp + (size_t)16 * K_ + kb + 32);
        short8 a80 = *(const short8*)(&sA[lr][kb + lc * 8]);
        short8 a81 = *(const short8*)(&sA[lr][kb + 32 + lc * 8]);
        acc0 = __builtin_amdgcn_mfma_f32_16x16x32_bf16(a80, b00, acc0, 0, 0, 0);
        acc1 = __builtin_amdgcn_mfma_f32_16x16x32_bf16(a80, b01, acc1, 0, 0, 0);
        acc0 = __builtin_amdgcn_mfma_f32_16x16x32_bf16(a81, b10, acc0, 0, 0, 0);
        acc1 = __builtin_amdgcn_mfma_f32_16x16x32_bf16(a81, b11, acc1, 0, 0, 0);
    }

    #pragma unroll
    for (int r = 0; r < 4; ++r) {
        int row = t0 + lc * 4 + r;
        chat[((size_t)(b * T_ + row)) * H_ + h0 + lr]      = acc0[r];
        chat[((size_t)(b * T_ + row)) * H_ + h0 + 16 + lr] = acc1[r];
    }
}

// ---------------------------------------------------------------------------
extern "C" void kernel_launch(void* const* d_in, const int* in_sizes, int n_in,
                              void* d_out, int out_size, void* d_ws, size_t ws_size,
                              hipStream_t stream) {
    const float* des   = (const float*)d_in[0];
    const float* title = (const float*)d_in[1];
    const float* Wv    = (const float*)d_in[2];
    const float* Wg    = (const float*)d_in[3];
    const float* Wh    = (const float*)d_in[4];

    float* chat  = (float*)d_out;                            // (B,T,H)
    float* alpha = (float*)d_out + (size_t)B_ * T_ * H_;     // (B,T,K)

    char* ws = (char*)d_ws;
    float*  cvT  = (float*)ws;                               // (B,64,K) f32: 1 MB
    float*  cg   = cvT + (size_t)B_ * APAD * K_;             // (B*T,64) f32: 1 MB
    ushort* desT = (ushort*)(cg + (size_t)B_ * T_ * APAD);   // (B,H,K) bf16: 4 MB
    ushort* Whl  = desT + (size_t)B_ * H_ * K_;              // [2][2][64][512]: 256 KB

    hipLaunchKernelGGL(kW, dim3(128), dim3(256), 0, stream, Wv, Wg, Whl);
    hipLaunchKernelGGL(kAP, dim3(2560), dim3(256), 0, stream,
                       des, title, Whl, cvT, cg, desT);
    hipLaunchKernelGGL(kZ, dim3(B_ * (T_ / 16)), dim3(1024), 0, stream,
                       cvT, cg, Wh, desT, alpha, chat);
}

// Round 11
// 61.296 us; speedup vs baseline: 1.9048x; 1.5606x over previous
//
#include <hip/hip_runtime.h>
#include <hip/hip_bf16.h>

// Problem constants (Atten_tit): B=16, T=256, K=256, H=512, A=49
#define B_ 16
#define T_ 256
#define K_ 256
#define H_ 512
#define A_ 49
#define APAD 64

typedef __attribute__((ext_vector_type(8))) short short8;   // bf16x8
typedef __attribute__((ext_vector_type(4))) float f32x4;

__device__ __forceinline__ ushort f2bf(float f) {
    uint u = __builtin_bit_cast(uint, f);
    u += 0x7FFF + ((u >> 16) & 1);   // RNE
    return (ushort)(u >> 16);
}

// split f32 -> bf16 hi + bf16 lo (residual); hi+lo ~ 17 mantissa bits.
__device__ __forceinline__ void cvt_hilo(float4 v0, float4 v1, short8& hi, short8& lo) {
    float v[8] = {v0.x, v0.y, v0.z, v0.w, v1.x, v1.y, v1.z, v1.w};
    #pragma unroll
    for (int i = 0; i < 8; ++i) {
        ushort h = f2bf(v[i]);
        float hf = __builtin_bit_cast(float, (uint)h << 16);
        hi[i] = (short)h;
        lo[i] = (short)f2bf(v[i] - hf);
    }
}

// 1/(exp(2x)+1); tanh(x) = 1 - 2*sig2(x). exp saturation handles extremes.
__device__ __forceinline__ float sig2(float x) {
    float e = __expf(2.f * x);
    return __builtin_amdgcn_rcpf(e + 1.f);
}

// ---------------------------------------------------------------------------
// kW: Wv,Wg (49x512 f32) -> Whl[m][hl][64][512] bf16, rows >=49 zeroed.
__global__ __launch_bounds__(256) void kW(const float* __restrict__ Wv,
                                          const float* __restrict__ Wg,
                                          ushort* __restrict__ Whl)
{
    int blk = blockIdx.x;              // 0..127: m = blk>>6, row = blk&63
    int m = blk >> 6, row = blk & 63;
    const float* W = m ? Wg : Wv;
    int tid = threadIdx.x;
    ushort* hi = Whl + ((size_t)(m * 2 + 0) * 64 + row) * H_;
    ushort* lo = Whl + ((size_t)(m * 2 + 1) * 64 + row) * H_;
    #pragma unroll
    for (int c = tid; c < H_; c += 256) {
        float v = (row < A_) ? W[(size_t)row * H_ + c] : 0.f;
        ushort h = f2bf(v);
        float hf = __builtin_bit_cast(float, (uint)h << 16);
        hi[c] = h;
        lo[c] = f2bf(v - hf);
    }
}

// ---------------------------------------------------------------------------
// kAP: blocks [0,256): projection, split-bf16 MFMA, 2 tiles per wave sharing
//      the same W fragments (ILP-2). W from global Whl (L2-resident).
//        bid<128:  des tile pair (2bid, 2bid+1)   -> cvT (B,64,K)
//        bid>=128: title tile pair                -> cg (B*T,64)
//      blocks [256,2304): transpose des (B,K,H) f32 -> desT (B,H,K) bf16.
__global__ __launch_bounds__(256) void kAP(const float* __restrict__ des,
                                           const float* __restrict__ title,
                                           const ushort* __restrict__ Whl,
                                           float* __restrict__ cvT,
                                           float* __restrict__ cg,
                                           ushort* __restrict__ desT)
{
    __shared__ float Tls[32][33];
    int tid = threadIdx.x;

    if (blockIdx.x >= 256) {
        // ---- transpose branch (round-7 proven) ----
        int tb = blockIdx.x - 256;            // b(16) x kt(8) x ht(16)
        int b = tb >> 7, rem = tb & 127;
        int k0 = (rem >> 4) * 32, h0 = (rem & 15) * 32;
        int kk = tid >> 3, c4 = (tid & 7) * 4;
        float4 v = *(const float4*)(des + ((size_t)(b * K_ + k0 + kk) * H_) + h0 + c4);
        Tls[kk][c4 + 0] = v.x; Tls[kk][c4 + 1] = v.y;
        Tls[kk][c4 + 2] = v.z; Tls[kk][c4 + 3] = v.w;
        __syncthreads();
        int hh = tid >> 3;
        ushort4 o;
        o.x = f2bf(Tls[c4 + 0][hh]);
        o.y = f2bf(Tls[c4 + 1][hh]);
        o.z = f2bf(Tls[c4 + 2][hh]);
        o.w = f2bf(Tls[c4 + 3][hh]);
        *(ushort4*)(desT + ((size_t)(b * H_ + h0 + hh) * K_) + k0 + c4) = o;
        return;
    }

    // ---- projection branch: tile pair per wave ----
    int wv = tid >> 6, lane = tid & 63;
    int lr = lane & 15, lc = lane >> 4;
    int g = wv;                               // a-group 0..3
    bool isDes = blockIdx.x < 128;
    int tile0 = isDes ? blockIdx.x * 2 : 256 + (blockIdx.x - 128) * 2;
    int tile1 = tile0 + 1;

    const float* X0 = isDes ? (des + (size_t)tile0 * 16 * H_)
                            : (title + (size_t)(tile0 - 256) * 16 * H_);
    const float* X1 = X0 + (size_t)16 * H_;
    int m = isDes ? 0 : 1;
    const ushort* whiP = Whl + ((size_t)(m * 2 + 0) * 64 + g * 16 + lr) * H_ + lc * 8;
    const ushort* wloP = Whl + ((size_t)(m * 2 + 1) * 64 + g * 16 + lr) * H_ + lc * 8;
    const float*  xq0  = X0 + (size_t)lr * H_ + lc * 8;
    const float*  xq1  = X1 + (size_t)lr * H_ + lc * 8;

    f32x4 acc0 = {}, acc1 = {};

    #pragma unroll
    for (int i = 0; i < 16; ++i) {
        int k0 = i * 32;
        short8 whi = *(const short8*)(whiP + k0);
        short8 wlo = *(const short8*)(wloP + k0);
        float4 a0 = *(const float4*)(xq0 + k0);
        float4 a1 = *(const float4*)(xq0 + k0 + 4);
        float4 b0 = *(const float4*)(xq1 + k0);
        float4 b1 = *(const float4*)(xq1 + k0 + 4);
        short8 x0hi, x0lo, x1hi, x1lo;
        cvt_hilo(a0, a1, x0hi, x0lo);
        cvt_hilo(b0, b1, x1hi, x1lo);
        if (isDes) {     // A = W (rows=a), B = X (cols = k-row of des)
            acc0 = __builtin_amdgcn_mfma_f32_16x16x32_bf16(whi, x0hi, acc0, 0, 0, 0);
            acc1 = __builtin_amdgcn_mfma_f32_16x16x32_bf16(whi, x1hi, acc1, 0, 0, 0);
            acc0 = __builtin_amdgcn_mfma_f32_16x16x32_bf16(whi, x0lo, acc0, 0, 0, 0);
            acc1 = __builtin_amdgcn_mfma_f32_16x16x32_bf16(whi, x1lo, acc1, 0, 0, 0);
            acc0 = __builtin_amdgcn_mfma_f32_16x16x32_bf16(wlo, x0hi, acc0, 0, 0, 0);
            acc1 = __builtin_amdgcn_mfma_f32_16x16x32_bf16(wlo, x1hi, acc1, 0, 0, 0);
        } else {         // A = X (rows=t), B = W (cols=a)
            acc0 = __builtin_amdgcn_mfma_f32_16x16x32_bf16(x0hi, whi, acc0, 0, 0, 0);
            acc1 = __builtin_amdgcn_mfma_f32_16x16x32_bf16(x1hi, whi, acc1, 0, 0, 0);
            acc0 = __builtin_amdgcn_mfma_f32_16x16x32_bf16(x0lo, whi, acc0, 0, 0, 0);
            acc1 = __builtin_amdgcn_mfma_f32_16x16x32_bf16(x1lo, whi, acc1, 0, 0, 0);
            acc0 = __builtin_amdgcn_mfma_f32_16x16x32_bf16(x0hi, wlo, acc0, 0, 0, 0);
            acc1 = __builtin_amdgcn_mfma_f32_16x16x32_bf16(x1hi, wlo, acc1, 0, 0, 0);
        }
    }

    if (isDes) {
        #pragma unroll
        for (int p = 0; p < 2; ++p) {
            int krows = (tile0 + p) * 16;
            int b = krows >> 8, kb = krows & 255;
            f32x4 acc = p ? acc1 : acc0;
            #pragma unroll
            for (int r = 0; r < 4; ++r) {
                int a = g * 16 + lc * 4 + r;           // C row = a
                cvT[((size_t)b * APAD + a) * K_ + kb + lr] = acc[r];
            }
        }
    } else {
        #pragma unroll
        for (int p = 0; p < 2; ++p) {
            int trows = (tile0 + p - 256) * 16;        // global title row (b*T+t)
            f32x4 acc = p ? acc1 : acc0;
            #pragma unroll
            for (int r = 0; r < 4; ++r) {
                int row = trows + lc * 4 + r;          // C row = t
                cg[(size_t)row * APAD + g * 16 + lr] = acc[r];
            }
        }
    }
}

// ---------------------------------------------------------------------------
// kZ: fused z + softmax + PV. 512 blocks x 512 threads (2 blocks/CU so one
// block's compute overlaps another's staging/barriers). Block = (b = bid&15
// [XCD-homed], 8-row t-tile t0 = (bid>>4)*8).
// Thread (k = tid&255, tg = tid>>8 in {0,1}) owns t = tg*4 + {0..3}.
// z phase: all 49 cv values preloaded to registers (MLP=49), cg/Wh from LDS.
// PV: 8 waves x 64-h panels, A rows 8..15 zero-padded.
__global__ __launch_bounds__(512) void kZ(const float* __restrict__ cvT,
                                          const float* __restrict__ cg,
                                          const float* __restrict__ Wh,
                                          const ushort* __restrict__ desT,
                                          float* __restrict__ alpha,
                                          float* __restrict__ chat)
{
    __shared__ float  sCg[8][APAD];        // 2 KB
    __shared__ float  sWh[APAD];
    __shared__ float  sRedM[8][4];
    __shared__ float  sRedS[8][4];
    __shared__ ushort sA[16][K_ + 8];      // 8.4 KB

    int bid = blockIdx.x;                 // 512 blocks
    int b  = bid & 15;
    int t0 = (bid >> 4) * 8;
    int tid = threadIdx.x;
    int k  = tid & 255;
    int tg = tid >> 8;                    // 0..1
    int tb = tg * 4;

    if (tid < 128) {
        int row = tid >> 4, c = (tid & 15) * 4;
        *(float4*)(&sCg[row][c]) =
            *(const float4*)(cg + (size_t)(b * T_ + t0 + row) * APAD + c);
    } else if (tid < 128 + APAD) {
        int a = tid - 128;
        sWh[a] = (a < A_) ? Wh[a] : 0.f;
    }
    {   // zero sA rows 8..15 (PV A-operand has 16 rows; 8 real)
        uint* zp = (uint*)&sA[8][0];      // 8 x 264 ushort = 1056 uint
        #pragma unroll
        for (int i = tid; i < 1056; i += 512) zp[i] = 0;
    }
    __syncthreads();

    // ---- preload all 49 cv values (independent loads -> MLP) ----
    const float* cvp = cvT + (size_t)b * APAD * K_ + k;
    float xa[A_];
    #pragma unroll
    for (int a = 0; a < A_; ++a) xa[a] = cvp[(size_t)a * K_];

    // ---- z phase: a blocked by 8, 4 t's per thread ----
    float zacc[4] = {0.f, 0.f, 0.f, 0.f};
    #pragma unroll
    for (int c6 = 0; c6 < 6; ++c6) {      // a = 0..47
        int a0 = c6 * 8;
        float4 w0 = *(const float4*)&sWh[a0];
        float4 w1 = *(const float4*)&sWh[a0 + 4];
        #pragma unroll
        for (int j = 0; j < 4; ++j) {
            float4 c0 = *(const float4*)&sCg[tb + j][a0];
            float4 c1 = *(const float4*)&sCg[tb + j][a0 + 4];
            zacc[j] += w0.x * sig2(xa[a0 + 0] + c0.x) + w0.y * sig2(xa[a0 + 1] + c0.y)
                     + w0.z * sig2(xa[a0 + 2] + c0.z) + w0.w * sig2(xa[a0 + 3] + c0.w)
                     + w1.x * sig2(xa[a0 + 4] + c1.x) + w1.y * sig2(xa[a0 + 5] + c1.y)
                     + w1.z * sig2(xa[a0 + 6] + c1.z) + w1.w * sig2(xa[a0 + 7] + c1.w);
        }
    }
    {   // tail a = 48
        float wh = sWh[48];
        #pragma unroll
        for (int j = 0; j < 4; ++j)
            zacc[j] += wh * sig2(xa[48] + sCg[tb + j][48]);
    }
    float sw = 0.f;
    #pragma unroll
    for (int q = 0; q < 16; ++q) {
        float4 w4 = *(const float4*)&sWh[q * 4];
        sw += w4.x + w4.y + w4.z + w4.w;
    }
    float z[4];
    #pragma unroll
    for (int j = 0; j < 4; ++j) z[j] = sw - 2.f * zacc[j];

    // ---- softmax over k (4 waves per tg group) ----
    int wv = tid >> 6, lane = tid & 63, w3 = wv & 3;
    #pragma unroll
    for (int j = 0; j < 4; ++j) {
        float m = z[j];
        #pragma unroll
        for (int off = 32; off > 0; off >>= 1) m = fmaxf(m, __shfl_xor(m, off));
        if (lane == 0) sRedM[tb + j][w3] = m;
    }
    __syncthreads();
    #pragma unroll
    for (int j = 0; j < 4; ++j) {
        int t = tb + j;
        float m = fmaxf(fmaxf(sRedM[t][0], sRedM[t][1]),
                        fmaxf(sRedM[t][2], sRedM[t][3]));
        z[j] = __expf(z[j] - m);
    }
    #pragma unroll
    for (int j = 0; j < 4; ++j) {
        float s = z[j];
        #pragma unroll
        for (int off = 32; off > 0; off >>= 1) s += __shfl_xor(s, off);
        if (lane == 0) sRedS[tb + j][w3] = s;
    }
    __syncthreads();
    #pragma unroll
    for (int j = 0; j < 4; ++j) {
        int t = tb + j;
        float s = sRedS[t][0] + sRedS[t][1] + sRedS[t][2] + sRedS[t][3];
        float rs = __builtin_amdgcn_rcpf(s);
        rs = rs * (2.f - s * rs);              // Newton step
        float al = z[j] * rs;
        alpha[(size_t)(b * T_ + t0 + t) * K_ + k] = al;
        sA[t][k] = f2bf(al);
    }
    __syncthreads();

    // ---- PV: wave wv -> h-panel [wv*64, +64), chunked load-all-then-MFMA ----
    int lr = lane & 15, lc = lane >> 4;
    int h0 = wv * 64;
    const ushort* Bp = desT + ((size_t)(b * H_ + h0 + lr)) * K_ + lc * 8;

    f32x4 acc[4] = {};
    #pragma unroll
    for (int half = 0; half < 2; ++half) {
        int kb0 = half * 128;
        short8 bf[4][4];
        #pragma unroll
        for (int j = 0; j < 4; ++j)
            #pragma unroll
            for (int s = 0; s < 4; ++s)
                bf[j][s] = *(const short8*)(Bp + (size_t)(j * 16) * K_ + kb0 + s * 32);
        short8 af[4];
        #pragma unroll
        for (int s = 0; s < 4; ++s)
            af[s] = *(const short8*)(&sA[lr][kb0 + s * 32 + lc * 8]);
        #pragma unroll
        for (int s = 0; s < 4; ++s)
            #pragma unroll
            for (int j = 0; j < 4; ++j)
                acc[j] = __builtin_amdgcn_mfma_f32_16x16x32_bf16(af[s], bf[j][s], acc[j], 0, 0, 0);
    }

    #pragma unroll
    for (int j = 0; j < 4; ++j) {
        #pragma unroll
        for (int r = 0; r < 4; ++r) {
            int row = lc * 4 + r;
            if (row < 8)
                chat[((size_t)(b * T_ + t0 + row)) * H_ + h0 + j * 16 + lr] = acc[j][r];
        }
    }
}

// ---------------------------------------------------------------------------
extern "C" void kernel_launch(void* const* d_in, const int* in_sizes, int n_in,
                              void* d_out, int out_size, void* d_ws, size_t ws_size,
                              hipStream_t stream) {
    const float* des   = (const float*)d_in[0];
    const float* title = (const float*)d_in[1];
    const float* Wv    = (const float*)d_in[2];
    const float* Wg    = (const float*)d_in[3];
    const float* Wh    = (const float*)d_in[4];

    float* chat  = (float*)d_out;                            // (B,T,H)
    float* alpha = (float*)d_out + (size_t)B_ * T_ * H_;     // (B,T,K)

    char* ws = (char*)d_ws;
    float*  cvT  = (float*)ws;                               // (B,64,K) f32: 1 MB
    float*  cg   = cvT + (size_t)B_ * APAD * K_;             // (B*T,64) f32: 1 MB
    ushort* desT = (ushort*)(cg + (size_t)B_ * T_ * APAD);   // (B,H,K) bf16: 4 MB
    ushort* Whl  = desT + (size_t)B_ * H_ * K_;              // [2][2][64][512]: 256 KB

    hipLaunchKernelGGL(kW, dim3(128), dim3(256), 0, stream, Wv, Wg, Whl);
    hipLaunchKernelGGL(kAP, dim3(2304), dim3(256), 0, stream,
                       des, title, Whl, cvT, cg, desT);
    hipLaunchKernelGGL(kZ, dim3(2 * B_ * (T_ / 16)), dim3(512), 0, stream,
                       cvT, cg, Wh, desT, alpha, chat);
}

// Round 12
// 56.859 us; speedup vs baseline: 2.0534x; 1.0780x over previous
//
#include <hip/hip_runtime.h>
#include <hip/hip_bf16.h>

// Problem constants (Atten_tit): B=16, T=256, K=256, H=512, A=49
#define B_ 16
#define T_ 256
#define K_ 256
#define H_ 512
#define A_ 49
#define APAD 64

typedef __attribute__((ext_vector_type(8))) short short8;   // bf16x8
typedef __attribute__((ext_vector_type(4))) float f32x4;

__device__ __forceinline__ ushort f2bf(float f) {
    uint u = __builtin_bit_cast(uint, f);
    u += 0x7FFF + ((u >> 16) & 1);   // RNE
    return (ushort)(u >> 16);
}

// split f32 -> bf16 hi + bf16 lo (residual); hi+lo ~ 17 mantissa bits.
__device__ __forceinline__ void cvt_hilo(float4 v0, float4 v1, short8& hi, short8& lo) {
    float v[8] = {v0.x, v0.y, v0.z, v0.w, v1.x, v1.y, v1.z, v1.w};
    #pragma unroll
    for (int i = 0; i < 8; ++i) {
        ushort h = f2bf(v[i]);
        float hf = __builtin_bit_cast(float, (uint)h << 16);
        hi[i] = (short)h;
        lo[i] = (short)f2bf(v[i] - hf);
    }
}

// 1/(exp(2x)+1); tanh(x) = 1 - 2*sig2(x). exp saturation handles extremes.
__device__ __forceinline__ float sig2(float x) {
    float e = __expf(2.f * x);
    return __builtin_amdgcn_rcpf(e + 1.f);
}

// ---------------------------------------------------------------------------
// kW: Wv,Wg (49x512 f32) -> Whl[m][hl][64][512] bf16, rows >=49 zeroed.
__global__ __launch_bounds__(256) void kW(const float* __restrict__ Wv,
                                          const float* __restrict__ Wg,
                                          ushort* __restrict__ Whl)
{
    int blk = blockIdx.x;              // 0..127: m = blk>>6, row = blk&63
    int m = blk >> 6, row = blk & 63;
    const float* W = m ? Wg : Wv;
    int tid = threadIdx.x;
    ushort* hi = Whl + ((size_t)(m * 2 + 0) * 64 + row) * H_;
    ushort* lo = Whl + ((size_t)(m * 2 + 1) * 64 + row) * H_;
    #pragma unroll
    for (int c = tid; c < H_; c += 256) {
        float v = (row < A_) ? W[(size_t)row * H_ + c] : 0.f;
        ushort h = f2bf(v);
        float hf = __builtin_bit_cast(float, (uint)h << 16);
        hi[c] = h;
        lo[c] = f2bf(v - hf);
    }
}

// ---------------------------------------------------------------------------
// kAP (round-7 exact): blocks [0,512): projection via split-bf16 MFMA,
//   1 tile/block, 1 a-group/wave, W from global Whl (L2-resident).
//     tiles 0..255   (des):   C = W x des-rows -> cvT (B,64,K)
//     tiles 256..511 (title): C = title-rows x W -> cg (B*T,64)
//   blocks [512,2560): transpose des (B,K,H) f32 -> desT (B,H,K) bf16.
__global__ __launch_bounds__(256) void kAP(const float* __restrict__ des,
                                           const float* __restrict__ title,
                                           const ushort* __restrict__ Whl,
                                           float* __restrict__ cvT,
                                           float* __restrict__ cg,
                                           ushort* __restrict__ desT)
{
    __shared__ float Tls[32][33];
    int tid = threadIdx.x;

    if (blockIdx.x >= 512) {
        // ---- transpose branch ----
        int tb = blockIdx.x - 512;            // b(16) x kt(8) x ht(16)
        int b = tb >> 7, rem = tb & 127;
        int k0 = (rem >> 4) * 32, h0 = (rem & 15) * 32;
        int kk = tid >> 3, c4 = (tid & 7) * 4;
        float4 v = *(const float4*)(des + ((size_t)(b * K_ + k0 + kk) * H_) + h0 + c4);
        Tls[kk][c4 + 0] = v.x; Tls[kk][c4 + 1] = v.y;
        Tls[kk][c4 + 2] = v.z; Tls[kk][c4 + 3] = v.w;
        __syncthreads();
        int hh = tid >> 3;
        ushort4 o;
        o.x = f2bf(Tls[c4 + 0][hh]);
        o.y = f2bf(Tls[c4 + 1][hh]);
        o.z = f2bf(Tls[c4 + 2][hh]);
        o.w = f2bf(Tls[c4 + 3][hh]);
        *(ushort4*)(desT + ((size_t)(b * H_ + h0 + hh) * K_) + k0 + c4) = o;
        return;
    }

    // ---- projection branch ----
    int wv = tid >> 6, lane = tid & 63;
    int tile = blockIdx.x;                    // 0..511
    bool isDes = tile < 256;
    int lr = lane & 15, lc = lane >> 4;
    int g = wv;                               // a-group 0..3

    const float* X = isDes ? (des + (size_t)tile * 16 * H_)
                           : (title + (size_t)(tile - 256) * 16 * H_);
    int m = isDes ? 0 : 1;
    const ushort* whiP = Whl + ((size_t)(m * 2 + 0) * 64 + g * 16 + lr) * H_ + lc * 8;
    const ushort* wloP = Whl + ((size_t)(m * 2 + 1) * 64 + g * 16 + lr) * H_ + lc * 8;
    const float*  xp0  = X + (size_t)lr * H_ + lc * 8;

    f32x4 acc = {};

    for (int k0 = 0; k0 < H_; k0 += 32) {
        float4 xv0 = *(const float4*)(xp0 + k0);
        float4 xv1 = *(const float4*)(xp0 + k0 + 4);
        short8 xhi, xlo;
        cvt_hilo(xv0, xv1, xhi, xlo);
        short8 whi = *(const short8*)(whiP + k0);
        short8 wlo = *(const short8*)(wloP + k0);
        if (isDes) {     // A = W (rows=a), B = X (cols = k-row of des)
            acc = __builtin_amdgcn_mfma_f32_16x16x32_bf16(whi, xhi, acc, 0, 0, 0);
            acc = __builtin_amdgcn_mfma_f32_16x16x32_bf16(whi, xlo, acc, 0, 0, 0);
            acc = __builtin_amdgcn_mfma_f32_16x16x32_bf16(wlo, xhi, acc, 0, 0, 0);
        } else {         // A = X (rows=t), B = W (cols=a)
            acc = __builtin_amdgcn_mfma_f32_16x16x32_bf16(xhi, whi, acc, 0, 0, 0);
            acc = __builtin_amdgcn_mfma_f32_16x16x32_bf16(xlo, whi, acc, 0, 0, 0);
            acc = __builtin_amdgcn_mfma_f32_16x16x32_bf16(xhi, wlo, acc, 0, 0, 0);
        }
    }

    if (isDes) {
        int krows = tile * 16;
        int b = krows >> 8, kb = krows & 255;
        #pragma unroll
        for (int r = 0; r < 4; ++r) {
            int a = g * 16 + lc * 4 + r;           // C row = a
            cvT[((size_t)b * APAD + a) * K_ + kb + lr] = acc[r];
        }
    } else {
        int trows = (tile - 256) * 16;             // global title row (b*T+t)
        #pragma unroll
        for (int r = 0; r < 4; ++r) {
            int row = trows + lc * 4 + r;          // C row = t
            cg[(size_t)row * APAD + g * 16 + lr] = acc[r];
        }
    }
}

// ---------------------------------------------------------------------------
// kZ: fused z + softmax + PV. 512 blocks x 512 threads (TT=8). b = bid&15
// (XCD-homed; keeps cvT[b]/desT[b] L2-local - FETCH was 3 MB in R11).
// Thread (k = tid&255, tg = tid>>8 in {0,1}) owns t = tg*4 + {0..3}.
// z phase: rolling 8-wide xa loads (no 49-reg preload -> VGPR ~70,
// 3+ blocks/CU so another block's z hides this block's barriers).
// PV: 8 waves x 64-h panels, per-j 4-deep B loads (low VGPR).
__global__ __launch_bounds__(512) void kZ(const float* __restrict__ cvT,
                                          const float* __restrict__ cg,
                                          const float* __restrict__ Wh,
                                          const ushort* __restrict__ desT,
                                          float* __restrict__ alpha,
                                          float* __restrict__ chat)
{
    __shared__ float  sCg[8][APAD];        // 2 KB
    __shared__ float  sWh[APAD];
    __shared__ float  sRedM[8][4];
    __shared__ float  sRedS[8][4];
    __shared__ ushort sA[16][K_ + 8];      // 8.4 KB

    int bid = blockIdx.x;                 // 512 blocks
    int b  = bid & 15;
    int t0 = (bid >> 4) * 8;
    int tid = threadIdx.x;
    int k  = tid & 255;
    int tg = tid >> 8;                    // 0..1
    int tb = tg * 4;

    if (tid < 128) {
        int row = tid >> 4, c = (tid & 15) * 4;
        *(float4*)(&sCg[row][c]) =
            *(const float4*)(cg + (size_t)(b * T_ + t0 + row) * APAD + c);
    } else if (tid < 128 + APAD) {
        int a = tid - 128;
        sWh[a] = (a < A_) ? Wh[a] : 0.f;
    }
    {   // zero sA rows 8..15 (PV A-operand has 16 rows; 8 real)
        uint* zp = (uint*)&sA[8][0];      // 8 x 264 ushort = 1056 uint
        #pragma unroll
        for (int i = tid; i < 1056; i += 512) zp[i] = 0;
    }
    __syncthreads();

    // ---- z phase: rolling 8-wide xa loads, 4 t's per thread ----
    const float* cvp = cvT + (size_t)b * APAD * K_ + k;
    float zacc[4] = {0.f, 0.f, 0.f, 0.f};

    for (int c6 = 0; c6 < 6; ++c6) {      // a = 0..47
        int a0 = c6 * 8;
        float xa[8];
        #pragma unroll
        for (int i = 0; i < 8; ++i) xa[i] = cvp[(size_t)(a0 + i) * K_];
        float4 w0 = *(const float4*)&sWh[a0];
        float4 w1 = *(const float4*)&sWh[a0 + 4];
        #pragma unroll
        for (int j = 0; j < 4; ++j) {
            float4 c0 = *(const float4*)&sCg[tb + j][a0];
            float4 c1 = *(const float4*)&sCg[tb + j][a0 + 4];
            zacc[j] += w0.x * sig2(xa[0] + c0.x) + w0.y * sig2(xa[1] + c0.y)
                     + w0.z * sig2(xa[2] + c0.z) + w0.w * sig2(xa[3] + c0.w)
                     + w1.x * sig2(xa[4] + c1.x) + w1.y * sig2(xa[5] + c1.y)
                     + w1.z * sig2(xa[6] + c1.z) + w1.w * sig2(xa[7] + c1.w);
        }
    }
    {   // tail a = 48
        float xa48 = cvp[(size_t)48 * K_];
        float wh = sWh[48];
        #pragma unroll
        for (int j = 0; j < 4; ++j)
            zacc[j] += wh * sig2(xa48 + sCg[tb + j][48]);
    }
    float sw = 0.f;
    #pragma unroll
    for (int q = 0; q < 16; ++q) {
        float4 w4 = *(const float4*)&sWh[q * 4];
        sw += w4.x + w4.y + w4.z + w4.w;
    }
    float z[4];
    #pragma unroll
    for (int j = 0; j < 4; ++j) z[j] = sw - 2.f * zacc[j];

    // ---- softmax over k (4 waves per tg group) ----
    int wv = tid >> 6, lane = tid & 63, w3 = wv & 3;
    #pragma unroll
    for (int j = 0; j < 4; ++j) {
        float m = z[j];
        #pragma unroll
        for (int off = 32; off > 0; off >>= 1) m = fmaxf(m, __shfl_xor(m, off));
        if (lane == 0) sRedM[tb + j][w3] = m;
    }
    __syncthreads();
    #pragma unroll
    for (int j = 0; j < 4; ++j) {
        int t = tb + j;
        float m = fmaxf(fmaxf(sRedM[t][0], sRedM[t][1]),
                        fmaxf(sRedM[t][2], sRedM[t][3]));
        z[j] = __expf(z[j] - m);
    }
    #pragma unroll
    for (int j = 0; j < 4; ++j) {
        float s = z[j];
        #pragma unroll
        for (int off = 32; off > 0; off >>= 1) s += __shfl_xor(s, off);
        if (lane == 0) sRedS[tb + j][w3] = s;
    }
    __syncthreads();
    #pragma unroll
    for (int j = 0; j < 4; ++j) {
        int t = tb + j;
        float s = sRedS[t][0] + sRedS[t][1] + sRedS[t][2] + sRedS[t][3];
        float rs = __builtin_amdgcn_rcpf(s);
        rs = rs * (2.f - s * rs);              // Newton step
        float al = z[j] * rs;
        alpha[(size_t)(b * T_ + t0 + t) * K_ + k] = al;
        sA[t][k] = f2bf(al);
    }
    __syncthreads();

    // ---- PV: wave wv -> h-panel [wv*64, +64), per-j 4-deep B loads ----
    int lr = lane & 15, lc = lane >> 4;
    int h0 = wv * 64;
    const ushort* Bp = desT + ((size_t)(b * H_ + h0 + lr)) * K_ + lc * 8;

    short8 af[8];
    #pragma unroll
    for (int s = 0; s < 8; ++s)
        af[s] = *(const short8*)(&sA[lr][s * 32 + lc * 8]);

    f32x4 acc[4] = {};
    #pragma unroll
    for (int j = 0; j < 4; ++j) {
        const ushort* Bj = Bp + (size_t)(j * 16) * K_;
        short8 bf[8];
        #pragma unroll
        for (int s = 0; s < 8; ++s)
            bf[s] = *(const short8*)(Bj + s * 32);
        #pragma unroll
        for (int s = 0; s < 8; ++s)
            acc[j] = __builtin_amdgcn_mfma_f32_16x16x32_bf16(af[s], bf[s], acc[j], 0, 0, 0);
    }

    #pragma unroll
    for (int j = 0; j < 4; ++j) {
        #pragma unroll
        for (int r = 0; r < 4; ++r) {
            int row = lc * 4 + r;
            if (row < 8)
                chat[((size_t)(b * T_ + t0 + row)) * H_ + h0 + j * 16 + lr] = acc[j][r];
        }
    }
}

// ---------------------------------------------------------------------------
extern "C" void kernel_launch(void* const* d_in, const int* in_sizes, int n_in,
                              void* d_out, int out_size, void* d_ws, size_t ws_size,
                              hipStream_t stream) {
    const float* des   = (const float*)d_in[0];
    const float* title = (const float*)d_in[1];
    const float* Wv    = (const float*)d_in[2];
    const float* Wg    = (const float*)d_in[3];
    const float* Wh    = (const float*)d_in[4];

    float* chat  = (float*)d_out;                            // (B,T,H)
    float* alpha = (float*)d_out + (size_t)B_ * T_ * H_;     // (B,T,K)

    char* ws = (char*)d_ws;
    float*  cvT  = (float*)ws;                               // (B,64,K) f32: 1 MB
    float*  cg   = cvT + (size_t)B_ * APAD * K_;             // (B*T,64) f32: 1 MB
    ushort* desT = (ushort*)(cg + (size_t)B_ * T_ * APAD);   // (B,H,K) bf16: 4 MB
    ushort* Whl  = desT + (size_t)B_ * H_ * K_;              // [2][2][64][512]: 256 KB

    hipLaunchKernelGGL(kW, dim3(128), dim3(256), 0, stream, Wv, Wg, Whl);
    hipLaunchKernelGGL(kAP, dim3(2560), dim3(256), 0, stream,
                       des, title, Whl, cvT, cg, desT);
    hipLaunchKernelGGL(kZ, dim3(2 * B_ * (T_ / 16)), dim3(512), 0, stream,
                       cvT, cg, Wh, desT, alpha, chat);
}

// Round 13
// 52.230 us; speedup vs baseline: 2.2354x; 1.0886x over previous
//
#include <hip/hip_runtime.h>
#include <hip/hip_bf16.h>

// Problem constants (Atten_tit): B=16, T=256, K=256, H=512, A=49
#define B_ 16
#define T_ 256
#define K_ 256
#define H_ 512
#define A_ 49
#define APAD 64

typedef __attribute__((ext_vector_type(8))) short short8;   // bf16x8
typedef __attribute__((ext_vector_type(4))) float f32x4;

__device__ __forceinline__ ushort f2bf(float f) {
    uint u = __builtin_bit_cast(uint, f);
    u += 0x7FFF + ((u >> 16) & 1);   // RNE
    return (ushort)(u >> 16);
}

// split f32 -> bf16 hi + bf16 lo (residual); hi+lo ~ 17 mantissa bits.
__device__ __forceinline__ void cvt_hilo(float4 v0, float4 v1, short8& hi, short8& lo) {
    float v[8] = {v0.x, v0.y, v0.z, v0.w, v1.x, v1.y, v1.z, v1.w};
    #pragma unroll
    for (int i = 0; i < 8; ++i) {
        ushort h = f2bf(v[i]);
        float hf = __builtin_bit_cast(float, (uint)h << 16);
        hi[i] = (short)h;
        lo[i] = (short)f2bf(v[i] - hf);
    }
}

// 1/(exp(2x)+1); tanh(x) = 1 - 2*sig2(x). exp saturation handles extremes.
__device__ __forceinline__ float sig2(float x) {
    float e = __expf(2.f * x);
    return __builtin_amdgcn_rcpf(e + 1.f);
}

// ---------------------------------------------------------------------------
// kW: Wv,Wg (49x512 f32) -> Whl[m][hl][64][512] bf16, rows >=49 zeroed.
__global__ __launch_bounds__(256) void kW(const float* __restrict__ Wv,
                                          const float* __restrict__ Wg,
                                          ushort* __restrict__ Whl)
{
    int blk = blockIdx.x;              // 0..127: m = blk>>6, row = blk&63
    int m = blk >> 6, row = blk & 63;
    const float* W = m ? Wg : Wv;
    int tid = threadIdx.x;
    ushort* hi = Whl + ((size_t)(m * 2 + 0) * 64 + row) * H_;
    ushort* lo = Whl + ((size_t)(m * 2 + 1) * 64 + row) * H_;
    #pragma unroll
    for (int c = tid; c < H_; c += 256) {
        float v = (row < A_) ? W[(size_t)row * H_ + c] : 0.f;
        ushort h = f2bf(v);
        float hf = __builtin_bit_cast(float, (uint)h << 16);
        hi[c] = h;
        lo[c] = f2bf(v - hf);
    }
}

// ---------------------------------------------------------------------------
// kAP: blocks [0,512): projection via split-bf16 MFMA. X tile (16x512)
//   converted to hi/lo bf16 in LDS ONCE per block (coalesced, 32 el/thread);
//   per-wave k-loop is then pure {2 global W (L2) + 2 LDS b128 + 3 MFMA}.
//     tiles 0..255   (des):   C = W x des-rows -> cvT (B,64,K)
//     tiles 256..511 (title): C = title-rows x W -> cg (B*T,64)
//   blocks [512,2560): transpose des (B,K,H) f32 -> desT (B,H,K) bf16.
#define XPAD 520   // ushort stride (+8): rows land 4 banks apart -> 2-way, free
union UAP {
    struct { ushort hi[16][XPAD]; ushort lo[16][XPAD]; } x;   // 33280 B
    float tls[32][33];                                        // 4224 B
};

__global__ __launch_bounds__(256) void kAP(const float* __restrict__ des,
                                           const float* __restrict__ title,
                                           const ushort* __restrict__ Whl,
                                           float* __restrict__ cvT,
                                           float* __restrict__ cg,
                                           ushort* __restrict__ desT)
{
    __shared__ UAP u;
    int tid = threadIdx.x;

    if (blockIdx.x >= 512) {
        // ---- transpose branch (round-7 proven) ----
        int tb = blockIdx.x - 512;            // b(16) x kt(8) x ht(16)
        int b = tb >> 7, rem = tb & 127;
        int k0 = (rem >> 4) * 32, h0 = (rem & 15) * 32;
        int kk = tid >> 3, c4 = (tid & 7) * 4;
        float4 v = *(const float4*)(des + ((size_t)(b * K_ + k0 + kk) * H_) + h0 + c4);
        u.tls[kk][33 * 0 + c4 + 0] = v.x;   // u.tls[kk][c4+i]
        u.tls[kk][c4 + 1] = v.y;
        u.tls[kk][c4 + 2] = v.z;
        u.tls[kk][c4 + 3] = v.w;
        __syncthreads();
        int hh = tid >> 3;
        ushort4 o;
        o.x = f2bf(u.tls[c4 + 0][hh]);
        o.y = f2bf(u.tls[c4 + 1][hh]);
        o.z = f2bf(u.tls[c4 + 2][hh]);
        o.w = f2bf(u.tls[c4 + 3][hh]);
        *(ushort4*)(desT + ((size_t)(b * H_ + h0 + hh) * K_) + k0 + c4) = o;
        return;
    }

    // ---- projection branch ----
    int tile = blockIdx.x;                    // 0..511
    bool isDes = tile < 256;
    const float* Xbase = isDes ? (des + (size_t)tile * 16 * H_)
                               : (title + (size_t)(tile - 256) * 16 * H_);

    {   // stage X tile as hi/lo bf16: 8192 els, 32/thread, coalesced
        #pragma unroll
        for (int it = 0; it < 4; ++it) {
            int eidx = it * 2048 + tid * 8;
            int r = eidx >> 9, c = eidx & 511;
            const float* p = Xbase + (size_t)r * H_ + c;
            float4 v0 = *(const float4*)(p);
            float4 v1 = *(const float4*)(p + 4);
            short8 hi, lo;
            cvt_hilo(v0, v1, hi, lo);
            *(short8*)&u.x.hi[r][c] = hi;
            *(short8*)&u.x.lo[r][c] = lo;
        }
    }
    __syncthreads();

    int wv = tid >> 6, lane = tid & 63;
    int lr = lane & 15, lc = lane >> 4;
    int g = wv;                               // a-group 0..3
    int m = isDes ? 0 : 1;
    const ushort* whiP = Whl + ((size_t)(m * 2 + 0) * 64 + g * 16 + lr) * H_ + lc * 8;
    const ushort* wloP = Whl + ((size_t)(m * 2 + 1) * 64 + g * 16 + lr) * H_ + lc * 8;

    f32x4 acc = {};
    #pragma unroll 4
    for (int k0 = 0; k0 < H_; k0 += 32) {
        short8 whi = *(const short8*)(whiP + k0);
        short8 wlo = *(const short8*)(wloP + k0);
        short8 xhi = *(const short8*)&u.x.hi[lr][k0 + lc * 8];
        short8 xlo = *(const short8*)&u.x.lo[lr][k0 + lc * 8];
        if (isDes) {     // A = W (rows=a), B = X (cols = k-row of des)
            acc = __builtin_amdgcn_mfma_f32_16x16x32_bf16(whi, xhi, acc, 0, 0, 0);
            acc = __builtin_amdgcn_mfma_f32_16x16x32_bf16(whi, xlo, acc, 0, 0, 0);
            acc = __builtin_amdgcn_mfma_f32_16x16x32_bf16(wlo, xhi, acc, 0, 0, 0);
        } else {         // A = X (rows=t), B = W (cols=a)
            acc = __builtin_amdgcn_mfma_f32_16x16x32_bf16(xhi, whi, acc, 0, 0, 0);
            acc = __builtin_amdgcn_mfma_f32_16x16x32_bf16(xlo, whi, acc, 0, 0, 0);
            acc = __builtin_amdgcn_mfma_f32_16x16x32_bf16(xhi, wlo, acc, 0, 0, 0);
        }
    }

    if (isDes) {
        int krows = tile * 16;
        int b = krows >> 8, kb = krows & 255;
        #pragma unroll
        for (int r = 0; r < 4; ++r) {
            int a = g * 16 + lc * 4 + r;           // C row = a
            cvT[((size_t)b * APAD + a) * K_ + kb + lr] = acc[r];
        }
    } else {
        int trows = (tile - 256) * 16;             // global title row (b*T+t)
        #pragma unroll
        for (int r = 0; r < 4; ++r) {
            int row = trows + lc * 4 + r;          // C row = t
            cg[(size_t)row * APAD + g * 16 + lr] = acc[r];
        }
    }
}

// ---------------------------------------------------------------------------
// kZ (round-12 exact): fused z + softmax + PV. 512 blocks x 512 threads (TT=8).
// b = bid&15 (XCD-homed; FETCH was 3 MB). Thread (k=tid&255, tg=tid>>8) owns
// t = tg*4 + {0..3}. Rolling 8-wide xa loads. PV: 8 waves x 64-h panels.
__global__ __launch_bounds__(512) void kZ(const float* __restrict__ cvT,
                                          const float* __restrict__ cg,
                                          const float* __restrict__ Wh,
                                          const ushort* __restrict__ desT,
                                          float* __restrict__ alpha,
                                          float* __restrict__ chat)
{
    __shared__ float  sCg[8][APAD];        // 2 KB
    __shared__ float  sWh[APAD];
    __shared__ float  sRedM[8][4];
    __shared__ float  sRedS[8][4];
    __shared__ ushort sA[16][K_ + 8];      // 8.4 KB

    int bid = blockIdx.x;                 // 512 blocks
    int b  = bid & 15;
    int t0 = (bid >> 4) * 8;
    int tid = threadIdx.x;
    int k  = tid & 255;
    int tg = tid >> 8;                    // 0..1
    int tb = tg * 4;

    if (tid < 128) {
        int row = tid >> 4, c = (tid & 15) * 4;
        *(float4*)(&sCg[row][c]) =
            *(const float4*)(cg + (size_t)(b * T_ + t0 + row) * APAD + c);
    } else if (tid < 128 + APAD) {
        int a = tid - 128;
        sWh[a] = (a < A_) ? Wh[a] : 0.f;
    }
    {   // zero sA rows 8..15 (PV A-operand has 16 rows; 8 real)
        uint* zp = (uint*)&sA[8][0];      // 8 x 264 ushort = 1056 uint
        #pragma unroll
        for (int i = tid; i < 1056; i += 512) zp[i] = 0;
    }
    __syncthreads();

    // ---- z phase: rolling 8-wide xa loads, 4 t's per thread ----
    const float* cvp = cvT + (size_t)b * APAD * K_ + k;
    float zacc[4] = {0.f, 0.f, 0.f, 0.f};

    for (int c6 = 0; c6 < 6; ++c6) {      // a = 0..47
        int a0 = c6 * 8;
        float xa[8];
        #pragma unroll
        for (int i = 0; i < 8; ++i) xa[i] = cvp[(size_t)(a0 + i) * K_];
        float4 w0 = *(const float4*)&sWh[a0];
        float4 w1 = *(const float4*)&sWh[a0 + 4];
        #pragma unroll
        for (int j = 0; j < 4; ++j) {
            float4 c0 = *(const float4*)&sCg[tb + j][a0];
            float4 c1 = *(const float4*)&sCg[tb + j][a0 + 4];
            zacc[j] += w0.x * sig2(xa[0] + c0.x) + w0.y * sig2(xa[1] + c0.y)
                     + w0.z * sig2(xa[2] + c0.z) + w0.w * sig2(xa[3] + c0.w)
                     + w1.x * sig2(xa[4] + c1.x) + w1.y * sig2(xa[5] + c1.y)
                     + w1.z * sig2(xa[6] + c1.z) + w1.w * sig2(xa[7] + c1.w);
        }
    }
    {   // tail a = 48
        float xa48 = cvp[(size_t)48 * K_];
        float wh = sWh[48];
        #pragma unroll
        for (int j = 0; j < 4; ++j)
            zacc[j] += wh * sig2(xa48 + sCg[tb + j][48]);
    }
    float sw = 0.f;
    #pragma unroll
    for (int q = 0; q < 16; ++q) {
        float4 w4 = *(const float4*)&sWh[q * 4];
        sw += w4.x + w4.y + w4.z + w4.w;
    }
    float z[4];
    #pragma unroll
    for (int j = 0; j < 4; ++j) z[j] = sw - 2.f * zacc[j];

    // ---- softmax over k (4 waves per tg group) ----
    int wv = tid >> 6, lane = tid & 63, w3 = wv & 3;
    #pragma unroll
    for (int j = 0; j < 4; ++j) {
        float m = z[j];
        #pragma unroll
        for (int off = 32; off > 0; off >>= 1) m = fmaxf(m, __shfl_xor(m, off));
        if (lane == 0) sRedM[tb + j][w3] = m;
    }
    __syncthreads();
    #pragma unroll
    for (int j = 0; j < 4; ++j) {
        int t = tb + j;
        float m = fmaxf(fmaxf(sRedM[t][0], sRedM[t][1]),
                        fmaxf(sRedM[t][2], sRedM[t][3]));
        z[j] = __expf(z[j] - m);
    }
    #pragma unroll
    for (int j = 0; j < 4; ++j) {
        float s = z[j];
        #pragma unroll
        for (int off = 32; off > 0; off >>= 1) s += __shfl_xor(s, off);
        if (lane == 0) sRedS[tb + j][w3] = s;
    }
    __syncthreads();
    #pragma unroll
    for (int j = 0; j < 4; ++j) {
        int t = tb + j;
        float s = sRedS[t][0] + sRedS[t][1] + sRedS[t][2] + sRedS[t][3];
        float rs = __builtin_amdgcn_rcpf(s);
        rs = rs * (2.f - s * rs);              // Newton step
        float al = z[j] * rs;
        alpha[(size_t)(b * T_ + t0 + t) * K_ + k] = al;
        sA[t][k] = f2bf(al);
    }
    __syncthreads();

    // ---- PV: wave wv -> h-panel [wv*64, +64), per-j 4-deep B loads ----
    int lr = lane & 15, lc = lane >> 4;
    int h0 = wv * 64;
    const ushort* Bp = desT + ((size_t)(b * H_ + h0 + lr)) * K_ + lc * 8;

    short8 af[8];
    #pragma unroll
    for (int s = 0; s < 8; ++s)
        af[s] = *(const short8*)(&sA[lr][s * 32 + lc * 8]);

    f32x4 acc[4] = {};
    #pragma unroll
    for (int j = 0; j < 4; ++j) {
        const ushort* Bj = Bp + (size_t)(j * 16) * K_;
        short8 bf[8];
        #pragma unroll
        for (int s = 0; s < 8; ++s)
            bf[s] = *(const short8*)(Bj + s * 32);
        #pragma unroll
        for (int s = 0; s < 8; ++s)
            acc[j] = __builtin_amdgcn_mfma_f32_16x16x32_bf16(af[s], bf[s], acc[j], 0, 0, 0);
    }

    #pragma unroll
    for (int j = 0; j < 4; ++j) {
        #pragma unroll
        for (int r = 0; r < 4; ++r) {
            int row = lc * 4 + r;
            if (row < 8)
                chat[((size_t)(b * T_ + t0 + row)) * H_ + h0 + j * 16 + lr] = acc[j][r];
        }
    }
}

// ---------------------------------------------------------------------------
extern "C" void kernel_launch(void* const* d_in, const int* in_sizes, int n_in,
                              void* d_out, int out_size, void* d_ws, size_t ws_size,
                              hipStream_t stream) {
    const float* des   = (const float*)d_in[0];
    const float* title = (const float*)d_in[1];
    const float* Wv    = (const float*)d_in[2];
    const float* Wg    = (const float*)d_in[3];
    const float* Wh    = (const float*)d_in[4];

    float* chat  = (float*)d_out;                            // (B,T,H)
    float* alpha = (float*)d_out + (size_t)B_ * T_ * H_;     // (B,T,K)

    char* ws = (char*)d_ws;
    float*  cvT  = (float*)ws;                               // (B,64,K) f32: 1 MB
    float*  cg   = cvT + (size_t)B_ * APAD * K_;             // (B*T,64) f32: 1 MB
    ushort* desT = (ushort*)(cg + (size_t)B_ * T_ * APAD);   // (B,H,K) bf16: 4 MB
    ushort* Whl  = desT + (size_t)B_ * H_ * K_;              // [2][2][64][512]: 256 KB

    hipLaunchKernelGGL(kW, dim3(128), dim3(256), 0, stream, Wv, Wg, Whl);
    hipLaunchKernelGGL(kAP, dim3(2560), dim3(256), 0, stream,
                       des, title, Whl, cvT, cg, desT);
    hipLaunchKernelGGL(kZ, dim3(2 * B_ * (T_ / 16)), dim3(512), 0, stream,
                       cvT, cg, Wh, desT, alpha, chat);
}